// Round 1
// baseline (829.189 us; speedup 1.0000x reference)
//
#include <hip/hip_runtime.h>
#include <math.h>

// VQ: v (8,2048,256) f32, w (4096,256) f32 softmax rows, row0 = 1/256.
// diff = v2 - 2 v.cb^T + c2 over codes 1..4095 (fp32, np semantics replicated
// bit-for-bit for v2/c2 and the final rounding chain); argmin ties -> lowest n.
// Outputs (flat f32): out[16384*256], idx[16384] (as float), loss, used=0.

#define M_TOTAL 16384
#define NCODES  4096
#define D_DIM   256

#define OUT_OFF_IDX  (M_TOTAL * D_DIM)            // 4194304
#define OUT_OFF_LOSS (OUT_OFF_IDX + M_TOTAL)      // 4210688

// ---- numpy pairwise_sum replication for a 128-float block of squares ----
__device__ __forceinline__ float pw128_sq(const float* __restrict__ a) {
  float r[8];
#pragma unroll
  for (int j = 0; j < 8; ++j) r[j] = __fmul_rn(a[j], a[j]);
#pragma unroll
  for (int i = 8; i < 128; i += 8) {
#pragma unroll
    for (int j = 0; j < 8; ++j) r[j] = __fadd_rn(r[j], __fmul_rn(a[i + j], a[i + j]));
  }
  return __fadd_rn(__fadd_rn(__fadd_rn(r[0], r[1]), __fadd_rn(r[2], r[3])),
                   __fadd_rn(__fadd_rn(r[4], r[5]), __fadd_rn(r[6], r[7])));
}

// sum(x[r]^2) over 256 cols, numpy pairwise order: pw(0:128) + pw(128:256)
__global__ void rowsq_kernel(const float* __restrict__ x, float* __restrict__ out, int rows) {
  int r = blockIdx.x * blockDim.x + threadIdx.x;
  if (r >= rows) return;
  const float* a = x + (size_t)r * D_DIM;
  out[r] = __fadd_rn(pw128_sq(a), pw128_sq(a + 128));
}

// ---- main: GEMM (M x N x K) + quantized-diff argmin epilogue ----
#define BM 64
#define BN 64
#define BK 16
#define LDSP 68   // BM+4: keeps rows 16B-aligned for float4 LDS reads

__global__ __launch_bounds__(256, 2) void vq_argmin_kernel(
    const float* __restrict__ V, const float* __restrict__ W,
    const float* __restrict__ v2, const float* __restrict__ c2,
    float* __restrict__ pval, int* __restrict__ pidx)
{
  __shared__ float As[BK][LDSP];
  __shared__ float Bs[BK][LDSP];
  __shared__ float rv[BM][16];
  __shared__ int   ri[BM][16];

  const int tid = threadIdx.x;
  const int tx = tid & 15;        // code group (4 codes)
  const int ty = tid >> 4;        // query group (4 queries)
  const int q0 = blockIdx.x * BM;
  const int half = blockIdx.y;
  const int nStart = half * (NCODES / 2);

  float best[4] = {INFINITY, INFINITY, INFINITY, INFINITY};
  int   bidx[4] = {0x7FFFFFFF, 0x7FFFFFFF, 0x7FFFFFFF, 0x7FFFFFFF};

  float v2r[4];
#pragma unroll
  for (int i = 0; i < 4; ++i) v2r[i] = v2[q0 + ty * 4 + i];

  const int lr = tid >> 2;          // 0..63 : tile row this thread stages
  const int lc = (tid & 3) * 4;     // 0,4,8,12 : k-offset (float4)

  for (int n0 = nStart; n0 < nStart + NCODES / 2; n0 += BN) {
    float acc[4][4];
#pragma unroll
    for (int i = 0; i < 4; ++i)
#pragma unroll
      for (int j = 0; j < 4; ++j) acc[i][j] = 0.0f;

    for (int k0 = 0; k0 < D_DIM; k0 += BK) {
      __syncthreads();
      float4 av = *(const float4*)(V + (size_t)(q0 + lr) * D_DIM + k0 + lc);
      float4 bv = *(const float4*)(W + (size_t)(n0 + lr) * D_DIM + k0 + lc);
      As[lc + 0][lr] = av.x; As[lc + 1][lr] = av.y; As[lc + 2][lr] = av.z; As[lc + 3][lr] = av.w;
      Bs[lc + 0][lr] = bv.x; Bs[lc + 1][lr] = bv.y; Bs[lc + 2][lr] = bv.z; Bs[lc + 3][lr] = bv.w;
      __syncthreads();
#pragma unroll
      for (int kk = 0; kk < BK; ++kk) {
        float4 a4 = *(const float4*)&As[kk][ty * 4];
        float4 b4 = *(const float4*)&Bs[kk][tx * 4];
        float ar[4] = {a4.x, a4.y, a4.z, a4.w};
        float br[4] = {b4.x, b4.y, b4.z, b4.w};
#pragma unroll
        for (int i = 0; i < 4; ++i)
#pragma unroll
          for (int j = 0; j < 4; ++j)
            acc[i][j] = fmaf(ar[i], br[j], acc[i][j]);
      }
    }
    // epilogue: diff = (v2 - 2*dot) + c2, each op fp32-rounded (np order)
#pragma unroll
    for (int j = 0; j < 4; ++j) {
      const int n = n0 + tx * 4 + j;
      const float c2n = c2[n];
#pragma unroll
      for (int i = 0; i < 4; ++i) {
        float t  = __fsub_rn(v2r[i], 2.0f * acc[i][j]);
        float dd = __fadd_rn(t, c2n);
        if (n == 0) dd = INFINITY;  // reference excludes code 0
        if (dd < best[i] || (dd == best[i] && n < bidx[i])) { best[i] = dd; bidx[i] = n; }
      }
    }
  }

  __syncthreads();
#pragma unroll
  for (int i = 0; i < 4; ++i) { rv[ty * 4 + i][tx] = best[i]; ri[ty * 4 + i][tx] = bidx[i]; }
  __syncthreads();
  if (tid < BM) {
    float bv = rv[tid][0]; int bi = ri[tid][0];
#pragma unroll
    for (int t = 1; t < 16; ++t) {
      float v = rv[tid][t]; int ii = ri[tid][t];
      if (v < bv || (v == bv && ii < bi)) { bv = v; bi = ii; }
    }
    pval[half * M_TOTAL + q0 + tid] = bv;
    pidx[half * M_TOTAL + q0 + tid] = bi;
  }
}

// ---- gather + mask + idx write + loss partial ----
__global__ __launch_bounds__(256) void gather_kernel(
    const float* __restrict__ V, const float* __restrict__ W,
    const float* __restrict__ pval, const int* __restrict__ pidx,
    float* __restrict__ out, float* __restrict__ outIdx,
    double* __restrict__ lossAcc)
{
  const int q = blockIdx.x;
  const int d = threadIdx.x;
  __shared__ int s_idx;
  __shared__ int s_any;
  __shared__ float red[256];
  if (d == 0) {
    float va = pval[q], vb = pval[M_TOTAL + q];
    int ia = pidx[q], ib = pidx[M_TOTAL + q];
    s_idx = (vb < va || (vb == va && ib < ia)) ? ib : ia;  // global lowest-index ties
    s_any = 0;
  }
  __syncthreads();
  const float vv = V[(size_t)q * D_DIM + d];
  if (vv != 0.00390625f) s_any = 1;   // any(v != 1/256)
  __syncthreads();
  const int idx = s_any ? s_idx : 0;
  const float o = W[(size_t)idx * D_DIM + d];
  out[(size_t)q * D_DIM + d] = o;
  if (d == 0) outIdx[q] = (float)idx;
  const float df = o - vv;
  red[d] = df * df;
  __syncthreads();
  for (int s = 128; s > 0; s >>= 1) {
    if (d < s) red[d] += red[d + s];
    __syncthreads();
  }
  if (d == 0) atomicAdd(lossAcc, (double)red[0]);
}

__global__ void finalize_kernel(const double* __restrict__ lossAcc, float* __restrict__ out) {
  out[0] = (float)(*lossAcc / (double)(M_TOTAL * D_DIM));  // loss
  out[1] = 0.0f;                                           // used
}

extern "C" void kernel_launch(void* const* d_in, const int* in_sizes, int n_in,
                              void* d_out, int out_size, void* d_ws, size_t ws_size,
                              hipStream_t stream) {
  const float* V = (const float*)d_in[0];   // 16384 x 256
  const float* W = (const float*)d_in[1];   // 4096 x 256
  float* out = (float*)d_out;

  char* ws = (char*)d_ws;
  float* c2   = (float*)(ws);                                  // 4096 f
  float* v2   = (float*)(ws + 16384);                          // 16384 f
  float* pval = (float*)(ws + 16384 + 65536);                  // 2*16384 f
  int*   pidx = (int*)  (ws + 16384 + 65536 + 131072);         // 2*16384 i
  double* lossAcc = (double*)(ws + 16384 + 65536 + 131072 + 131072);

  hipMemsetAsync(lossAcc, 0, sizeof(double), stream);
  rowsq_kernel<<<(NCODES + 255) / 256, 256, 0, stream>>>(W, c2, NCODES);
  rowsq_kernel<<<(M_TOTAL + 255) / 256, 256, 0, stream>>>(V, v2, M_TOTAL);
  vq_argmin_kernel<<<dim3(M_TOTAL / BM, 2), 256, 0, stream>>>(V, W, v2, c2, pval, pidx);
  gather_kernel<<<M_TOTAL, 256, 0, stream>>>(V, W, pval, pidx, out, out + OUT_OFF_IDX, lossAcc);
  finalize_kernel<<<1, 1, 0, stream>>>(lossAcc, out + OUT_OFF_LOSS);
}

// Round 2
// 518.199 us; speedup vs baseline: 1.6001x; 1.6001x over previous
//
#include <hip/hip_runtime.h>
#include <math.h>
#include <stdint.h>

// VQ: v (16384,256) f32, w (4096,256) f32 softmax rows, row0 = 1/256.
// diff = (v2 - 2*dot) + c2, fp32-rounded per np; argmin over codes 1..4095,
// ties -> lowest index (packed u64 lexicographic min). Outputs flat f32:
// out[16384*256], idx[16384], loss, used=0.

#define M_TOTAL 16384
#define NCODES  4096
#define D_DIM   256

#define OUT_OFF_IDX  (M_TOTAL * D_DIM)
#define OUT_OFF_LOSS (OUT_OFF_IDX + M_TOTAL)

#define BM 128
#define BN 128
#define BK 32
#define ASTRIDE 132   // BM + 4: keeps ds_read_b128 16B-aligned, staging writes 2-way
#define NPART 32      // N-dim grid splits -> partials per query

// ---- numpy pairwise_sum replication for a 128-float block of squares ----
__device__ __forceinline__ float pw128_sq(const float* __restrict__ a) {
  float r[8];
#pragma unroll
  for (int j = 0; j < 8; ++j) r[j] = __fmul_rn(a[j], a[j]);
#pragma unroll
  for (int i = 8; i < 128; i += 8) {
#pragma unroll
    for (int j = 0; j < 8; ++j) r[j] = __fadd_rn(r[j], __fmul_rn(a[i + j], a[i + j]));
  }
  return __fadd_rn(__fadd_rn(__fadd_rn(r[0], r[1]), __fadd_rn(r[2], r[3])),
                   __fadd_rn(__fadd_rn(r[4], r[5]), __fadd_rn(r[6], r[7])));
}

__global__ void rowsq_kernel(const float* __restrict__ x, float* __restrict__ out, int rows) {
  int r = blockIdx.x * blockDim.x + threadIdx.x;
  if (r >= rows) return;
  const float* a = x + (size_t)r * D_DIM;
  out[r] = __fadd_rn(pw128_sq(a), pw128_sq(a + 128));
}

// ---- main GEMM + argmin: 128x128x32 tile, 8x8 per thread (2x2 of 4x4) ----
__global__ __launch_bounds__(256, 3) void vq_argmin_kernel(
    const float* __restrict__ V, const float* __restrict__ W,
    const float* __restrict__ v2, const float* __restrict__ c2,
    uint64_t* __restrict__ pk)
{
  __shared__ float As[BK * ASTRIDE];
  __shared__ float Bs[BK * ASTRIDE];
  __shared__ uint64_t redP[BM * 16];   // 16 KB

  const int tid = threadIdx.x;
  const int tx = tid & 15;
  const int ty = tid >> 4;
  const int q0 = blockIdx.x * BM;
  const int n0 = blockIdx.y * BN;

  // ---- staging map: f = tid + 256u -> row = f>>3, kg = f&7 (8 f4 per row) ----
  float4 pa[4], pb[4];
#pragma unroll
  for (int u = 0; u < 4; ++u) {
    const int f = tid + 256 * u, row = f >> 3, kg = f & 7;
    pa[u] = *(const float4*)(V + (size_t)(q0 + row) * D_DIM + kg * 4);
    pb[u] = *(const float4*)(W + (size_t)(n0 + row) * D_DIM + kg * 4);
  }

  float acc[2][2][4][4];
#pragma unroll
  for (int p = 0; p < 2; ++p)
#pragma unroll
    for (int r = 0; r < 2; ++r)
#pragma unroll
      for (int i = 0; i < 4; ++i)
#pragma unroll
        for (int j = 0; j < 4; ++j) acc[p][r][i][j] = 0.0f;

  for (int k0 = 0; k0 < D_DIM; k0 += BK) {
    __syncthreads();
#pragma unroll
    for (int u = 0; u < 4; ++u) {
      const int f = tid + 256 * u, row = f >> 3, kg = f & 7;
      As[(kg * 4 + 0) * ASTRIDE + row] = pa[u].x;
      As[(kg * 4 + 1) * ASTRIDE + row] = pa[u].y;
      As[(kg * 4 + 2) * ASTRIDE + row] = pa[u].z;
      As[(kg * 4 + 3) * ASTRIDE + row] = pa[u].w;
      Bs[(kg * 4 + 0) * ASTRIDE + row] = pb[u].x;
      Bs[(kg * 4 + 1) * ASTRIDE + row] = pb[u].y;
      Bs[(kg * 4 + 2) * ASTRIDE + row] = pb[u].z;
      Bs[(kg * 4 + 3) * ASTRIDE + row] = pb[u].w;
    }
    __syncthreads();
    if (k0 + BK < D_DIM) {  // prefetch next tile into regs during compute
#pragma unroll
      for (int u = 0; u < 4; ++u) {
        const int f = tid + 256 * u, row = f >> 3, kg = f & 7;
        pa[u] = *(const float4*)(V + (size_t)(q0 + row) * D_DIM + k0 + BK + kg * 4);
        pb[u] = *(const float4*)(W + (size_t)(n0 + row) * D_DIM + k0 + BK + kg * 4);
      }
    }
#pragma unroll 8
    for (int kk = 0; kk < BK; ++kk) {
      float a[2][4], b[2][4];
      *(float4*)a[0] = *(const float4*)&As[kk * ASTRIDE + 4 * ty];
      *(float4*)a[1] = *(const float4*)&As[kk * ASTRIDE + 4 * ty + 64];
      *(float4*)b[0] = *(const float4*)&Bs[kk * ASTRIDE + 4 * tx];
      *(float4*)b[1] = *(const float4*)&Bs[kk * ASTRIDE + 4 * tx + 64];
#pragma unroll
      for (int p = 0; p < 2; ++p)
#pragma unroll
        for (int r = 0; r < 2; ++r)
#pragma unroll
          for (int i = 0; i < 4; ++i)
#pragma unroll
            for (int j = 0; j < 4; ++j)
              acc[p][r][i][j] = fmaf(a[p][i], b[r][j], acc[p][r][i][j]);
    }
  }

  // ---- epilogue: quantized diff + per-thread argmin over its 8 codes ----
  float v2q[2][4];
#pragma unroll
  for (int p = 0; p < 2; ++p)
#pragma unroll
    for (int i = 0; i < 4; ++i) v2q[p][i] = v2[q0 + 64 * p + 4 * ty + i];

  uint64_t best[2][4];
#pragma unroll
  for (int p = 0; p < 2; ++p)
#pragma unroll
    for (int i = 0; i < 4; ++i) best[p][i] = ~0ULL;

#pragma unroll
  for (int r = 0; r < 2; ++r)
#pragma unroll
    for (int j = 0; j < 4; ++j) {
      const int n = n0 + 64 * r + 4 * tx + j;
      const float c2n = c2[n];
#pragma unroll
      for (int p = 0; p < 2; ++p)
#pragma unroll
        for (int i = 0; i < 4; ++i) {
          float t  = __fsub_rn(v2q[p][i], 2.0f * acc[p][r][i][j]);
          float dd = __fadd_rn(t, c2n);
          if (n == 0) dd = INFINITY;  // reference excludes code 0
          uint64_t pkv = ((uint64_t)__float_as_uint(dd) << 32) | (uint32_t)n;
          if (pkv < best[p][i]) best[p][i] = pkv;  // diff>0 -> bits monotonic
        }
    }

#pragma unroll
  for (int p = 0; p < 2; ++p)
#pragma unroll
    for (int i = 0; i < 4; ++i) redP[(64 * p + 4 * ty + i) * 16 + tx] = best[p][i];
  __syncthreads();
  if (tid < BM) {
    uint64_t b = redP[tid * 16];
#pragma unroll
    for (int t = 1; t < 16; ++t) { uint64_t v = redP[tid * 16 + t]; if (v < b) b = v; }
    pk[blockIdx.y * M_TOTAL + q0 + tid] = b;
  }
}

// ---- gather + 32-way partial reduce + mask + idx + loss partial ----
__global__ __launch_bounds__(256) void gather_kernel(
    const float* __restrict__ V, const float* __restrict__ W,
    const uint64_t* __restrict__ pk,
    float* __restrict__ out, float* __restrict__ outIdx,
    float* __restrict__ lossPartial)
{
  const int q = blockIdx.x;
  const int d = threadIdx.x;
  __shared__ uint64_t sp[NPART];
  __shared__ int s_idx;
  __shared__ int s_any;
  __shared__ float red[256];
  if (d < NPART) sp[d] = pk[(size_t)d * M_TOTAL + q];
  if (d == 0) s_any = 0;
  __syncthreads();
  if (d == 0) {
    uint64_t b = sp[0];
#pragma unroll
    for (int t = 1; t < NPART; ++t) if (sp[t] < b) b = sp[t];
    s_idx = (int)(uint32_t)b;
  }
  const float vv = V[(size_t)q * D_DIM + d];
  if (vv != 0.00390625f) s_any = 1;   // any(v != 1/256); benign race
  __syncthreads();
  const int idx = s_any ? s_idx : 0;
  const float o = W[(size_t)idx * D_DIM + d];
  out[(size_t)q * D_DIM + d] = o;
  if (d == 0) outIdx[q] = (float)idx;
  const float df = o - vv;
  red[d] = df * df;
  __syncthreads();
  for (int s = 128; s > 0; s >>= 1) {
    if (d < s) red[d] += red[d + s];
    __syncthreads();
  }
  if (d == 0) lossPartial[q] = red[0];
}

__global__ __launch_bounds__(256) void finalize_kernel(
    const float* __restrict__ lossPartial, float* __restrict__ out)
{
  const int t = threadIdx.x;
  __shared__ float red[256];
  float s = 0.0f;
  for (int i = t; i < M_TOTAL; i += 256) s += lossPartial[i];
  red[t] = s;
  __syncthreads();
  for (int st = 128; st > 0; st >>= 1) {
    if (t < st) red[t] += red[t + st];
    __syncthreads();
  }
  if (t == 0) {
    out[0] = (float)((double)red[0] / (double)(M_TOTAL * D_DIM));  // loss
    out[1] = 0.0f;                                                 // used
  }
}

extern "C" void kernel_launch(void* const* d_in, const int* in_sizes, int n_in,
                              void* d_out, int out_size, void* d_ws, size_t ws_size,
                              hipStream_t stream) {
  const float* V = (const float*)d_in[0];   // 16384 x 256
  const float* W = (const float*)d_in[1];   // 4096 x 256
  float* out = (float*)d_out;

  char* ws = (char*)d_ws;
  float*    c2   = (float*)(ws);                         // 4096 f   (16 KB)
  float*    v2   = (float*)(ws + 16384);                 // 16384 f  (64 KB)
  uint64_t* pk   = (uint64_t*)(ws + 16384 + 65536);      // 32*16384 u64 (4 MB)
  float* lossPartial = (float*)(ws + 16384 + 65536 + (size_t)NPART * M_TOTAL * 8);

  rowsq_kernel<<<(NCODES + 255) / 256, 256, 0, stream>>>(W, c2, NCODES);
  rowsq_kernel<<<(M_TOTAL + 255) / 256, 256, 0, stream>>>(V, v2, M_TOTAL);
  vq_argmin_kernel<<<dim3(M_TOTAL / BM, NCODES / BN), 256, 0, stream>>>(V, W, v2, c2, pk);
  gather_kernel<<<M_TOTAL, 256, 0, stream>>>(V, W, pk, out, out + OUT_OFF_IDX, lossPartial);
  finalize_kernel<<<1, 256, 0, stream>>>(lossPartial, out + OUT_OFF_LOSS);
}

// Round 3
// 279.248 us; speedup vs baseline: 2.9694x; 1.8557x over previous
//
#include <hip/hip_runtime.h>
#include <hip/hip_fp16.h>
#include <math.h>
#include <stdint.h>

// VQ via f16x3 split MFMA: dot = (hi.hi + hi.lo + lo.hi) * 2^-20, planes = f16(1024*x).
// diff = (v2 - 2*dot) + c2 fp32-rounded per np; argmin codes 1..4095, ties -> lowest n.

#define M_TOTAL 16384
#define NCODES  4096
#define D_DIM   256

#define OUT_OFF_IDX  (M_TOTAL * D_DIM)
#define OUT_OFF_LOSS (OUT_OFF_IDX + M_TOTAL)

#define NPART 16          // n-dim grid splits (4096 / 256)
#define WPLANE (NCODES * D_DIM)

typedef _Float16 half8 __attribute__((ext_vector_type(8)));
typedef float    float4v __attribute__((ext_vector_type(4)));

// ---- numpy pairwise_sum replication for a 128-float block of squares ----
__device__ __forceinline__ float pw128_sq(const float* __restrict__ a) {
  float r[8];
#pragma unroll
  for (int j = 0; j < 8; ++j) r[j] = __fmul_rn(a[j], a[j]);
#pragma unroll
  for (int i = 8; i < 128; i += 8) {
#pragma unroll
    for (int j = 0; j < 8; ++j) r[j] = __fadd_rn(r[j], __fmul_rn(a[i + j], a[i + j]));
  }
  return __fadd_rn(__fadd_rn(__fadd_rn(r[0], r[1]), __fadd_rn(r[2], r[3])),
                   __fadd_rn(__fadd_rn(r[4], r[5]), __fadd_rn(r[6], r[7])));
}

__global__ void rowsq_kernel(const float* __restrict__ x, float* __restrict__ out, int rows) {
  int r = blockIdx.x * blockDim.x + threadIdx.x;
  if (r >= rows) return;
  const float* a = x + (size_t)r * D_DIM;
  out[r] = __fadd_rn(pw128_sq(a), pw128_sq(a + 128));
}

// ---- split W into scaled f16 hi/lo planes ----
__global__ __launch_bounds__(256) void wsplit_kernel(
    const float* __restrict__ W, _Float16* __restrict__ Whi, _Float16* __restrict__ Wlo)
{
  int i = blockIdx.x * 256 + threadIdx.x;
  float s = W[i] * 1024.0f;          // exact (pow2 scale)
  _Float16 h = (_Float16)s;          // RN
  Whi[i] = h;
  Wlo[i] = (_Float16)(s - (float)h); // RN of exact residual
}

// ---- main: MFMA f16x3 GEMM + quantized-diff argmin ----
// block 128m x 256n, 4 waves 2x2, wave tile 64m x 128n (mp 0..3, np 0..7)
__global__ __launch_bounds__(256, 2) void vq_mfma_kernel(
    const float* __restrict__ V, const _Float16* __restrict__ Whi,
    const float* __restrict__ v2, const float* __restrict__ c2,
    uint64_t* __restrict__ pk)
{
  __shared__ __align__(16) char smem[32768];
  _Float16* Ahi = (_Float16*)smem;            // 128 rows x 64 k  (16 KB)
  _Float16* Alo = (_Float16*)(smem + 16384);  // 16 KB
  uint64_t* red = (uint64_t*)smem;            // epilogue reuse: 128 x 32 u64

  const int tid  = threadIdx.x;
  const int lane = tid & 63;
  const int wave = tid >> 6;
  const int wr = wave >> 1, wc = wave & 1;
  const int row16 = lane & 15, quad = lane >> 4;
  const int m0 = blockIdx.x * 128;
  const int n0 = blockIdx.y * 256;

  float4v acc[4][8];
#pragma unroll
  for (int mp = 0; mp < 4; ++mp)
#pragma unroll
    for (int np = 0; np < 8; ++np) acc[mp][np] = (float4v)0.0f;

  for (int kt = 0; kt < 4; ++kt) {          // K-tiles of 64
    __syncthreads();                        // protect single-buffered LDS
    // ---- stage A tile: on-the-fly split, XOR-swizzled chunk layout ----
#pragma unroll
    for (int u = 0; u < 4; ++u) {
      const int g  = tid + 256 * u;         // chunk id 0..1023
      const int m  = g >> 3;                // local row 0..127
      const int kb = g & 7;                 // 8-half chunk within K-tile
      const int c  = kb ^ (m & 7);          // bank swizzle
      const float* src = V + (size_t)(m0 + m) * D_DIM + kt * 64 + kb * 8;
      float4 x0 = *(const float4*)src;
      float4 x1 = *(const float4*)(src + 4);
      float xs[8] = {x0.x, x0.y, x0.z, x0.w, x1.x, x1.y, x1.z, x1.w};
      union { half8 v; _Float16 e[8]; } uh, ul;
#pragma unroll
      for (int j = 0; j < 8; ++j) {
        float s = xs[j] * 1024.0f;          // exact
        _Float16 h = (_Float16)s;           // RN
        uh.e[j] = h;
        ul.e[j] = (_Float16)(s - (float)h); // RN of exact residual
      }
      *(half8*)(Ahi + m * 64 + c * 8) = uh.v;
      *(half8*)(Alo + m * 64 + c * 8) = ul.v;
    }
    __syncthreads();
    // ---- compute: 2 k-steps of 32 ----
#pragma unroll
    for (int ks = 0; ks < 2; ++ks) {
      half8 a_hi[4], a_lo[4];
#pragma unroll
      for (int mp = 0; mp < 4; ++mp) {
        const int m = wr * 64 + mp * 16 + row16;
        const int c = (ks * 4 + quad) ^ (m & 7);
        a_hi[mp] = *(const half8*)(Ahi + m * 64 + c * 8);
        a_lo[mp] = *(const half8*)(Alo + m * 64 + c * 8);
      }
#pragma unroll
      for (int np = 0; np < 8; ++np) {
        const _Float16* bp = Whi + (size_t)(n0 + wc * 128 + np * 16 + row16) * D_DIM
                             + kt * 64 + ks * 32 + quad * 8;
        half8 b_hi = *(const half8*)bp;
        half8 b_lo = *(const half8*)(bp + WPLANE);
#pragma unroll
        for (int mp = 0; mp < 4; ++mp) {
          acc[mp][np] = __builtin_amdgcn_mfma_f32_16x16x32_f16(a_hi[mp], b_hi, acc[mp][np], 0, 0, 0);
          acc[mp][np] = __builtin_amdgcn_mfma_f32_16x16x32_f16(a_hi[mp], b_lo, acc[mp][np], 0, 0, 0);
          acc[mp][np] = __builtin_amdgcn_mfma_f32_16x16x32_f16(a_lo[mp], b_hi, acc[mp][np], 0, 0, 0);
        }
      }
    }
  }

  // ---- epilogue: diff = (v2 - 2*dot) + c2 (np rounding order), argmin ----
  float v2r[4][4];
#pragma unroll
  for (int mp = 0; mp < 4; ++mp)
#pragma unroll
    for (int r = 0; r < 4; ++r)
      v2r[mp][r] = v2[m0 + wr * 64 + mp * 16 + quad * 4 + r];

  uint64_t best[4][4];
#pragma unroll
  for (int mp = 0; mp < 4; ++mp)
#pragma unroll
    for (int r = 0; r < 4; ++r) best[mp][r] = ~0ULL;

#pragma unroll
  for (int np = 0; np < 8; ++np) {
    const int n = n0 + wc * 128 + np * 16 + row16;
    const float c2n = c2[n];
#pragma unroll
    for (int mp = 0; mp < 4; ++mp)
#pragma unroll
      for (int r = 0; r < 4; ++r) {
        float dot = acc[mp][np][r] * 0x1p-20f;              // exact pow2 unscale
        float t   = __fsub_rn(v2r[mp][r], 2.0f * dot);
        float dd  = __fadd_rn(t, c2n);
        if (n == 0) dd = INFINITY;                          // exclude code 0
        uint64_t p = ((uint64_t)__float_as_uint(dd) << 32) | (uint32_t)n;
        if (p < best[mp][r]) best[mp][r] = p;               // dd>0 -> bits monotonic
      }
  }

  __syncthreads();   // all waves done reading A-LDS; reuse as reduction buffer
#pragma unroll
  for (int mp = 0; mp < 4; ++mp)
#pragma unroll
    for (int r = 0; r < 4; ++r)
      red[(wr * 64 + mp * 16 + quad * 4 + r) * 32 + wc * 16 + row16] = best[mp][r];
  __syncthreads();
  if (tid < 128) {
    uint64_t b = red[tid * 32];
#pragma unroll
    for (int t = 1; t < 32; ++t) { uint64_t v = red[tid * 32 + t]; if (v < b) b = v; }
    pk[blockIdx.y * M_TOTAL + m0 + tid] = b;
  }
}

// ---- gather + partial reduce + mask + idx + loss partial ----
__global__ __launch_bounds__(256) void gather_kernel(
    const float* __restrict__ V, const float* __restrict__ W,
    const uint64_t* __restrict__ pk,
    float* __restrict__ out, float* __restrict__ outIdx,
    float* __restrict__ lossPartial)
{
  const int q = blockIdx.x;
  const int d = threadIdx.x;
  __shared__ uint64_t sp[NPART];
  __shared__ int s_idx;
  __shared__ int s_any;
  __shared__ float red[256];
  if (d < NPART) sp[d] = pk[(size_t)d * M_TOTAL + q];
  if (d == 0) s_any = 0;
  __syncthreads();
  if (d == 0) {
    uint64_t b = sp[0];
#pragma unroll
    for (int t = 1; t < NPART; ++t) if (sp[t] < b) b = sp[t];
    s_idx = (int)(uint32_t)b;
  }
  const float vv = V[(size_t)q * D_DIM + d];
  if (vv != 0.00390625f) s_any = 1;   // any(v != 1/256); benign race
  __syncthreads();
  const int idx = s_any ? s_idx : 0;
  const float o = W[(size_t)idx * D_DIM + d];
  out[(size_t)q * D_DIM + d] = o;
  if (d == 0) outIdx[q] = (float)idx;
  const float df = o - vv;
  red[d] = df * df;
  __syncthreads();
  for (int s = 128; s > 0; s >>= 1) {
    if (d < s) red[d] += red[d + s];
    __syncthreads();
  }
  if (d == 0) lossPartial[q] = red[0];
}

__global__ __launch_bounds__(256) void finalize_kernel(
    const float* __restrict__ lossPartial, float* __restrict__ out)
{
  const int t = threadIdx.x;
  __shared__ float red[256];
  float s = 0.0f;
  for (int i = t; i < M_TOTAL; i += 256) s += lossPartial[i];
  red[t] = s;
  __syncthreads();
  for (int st = 128; st > 0; st >>= 1) {
    if (t < st) red[t] += red[t + st];
    __syncthreads();
  }
  if (t == 0) {
    out[0] = (float)((double)red[0] / (double)(M_TOTAL * D_DIM));  // loss
    out[1] = 0.0f;                                                 // used
  }
}

extern "C" void kernel_launch(void* const* d_in, const int* in_sizes, int n_in,
                              void* d_out, int out_size, void* d_ws, size_t ws_size,
                              hipStream_t stream) {
  const float* V = (const float*)d_in[0];   // 16384 x 256
  const float* W = (const float*)d_in[1];   // 4096 x 256
  float* out = (float*)d_out;

  char* ws = (char*)d_ws;
  _Float16* Whi = (_Float16*)(ws);                        // 2 MB
  _Float16* Wlo = (_Float16*)(ws + 2097152);              // 2 MB (= Whi + WPLANE)
  float*    c2  = (float*)(ws + 4194304);                 // 16 KB
  float*    v2  = (float*)(ws + 4194304 + 16384);         // 64 KB
  uint64_t* pk  = (uint64_t*)(ws + 4194304 + 16384 + 65536);          // 16*16384*8 = 2 MB
  float* lossPartial = (float*)(ws + 4194304 + 16384 + 65536 + 2097152);

  wsplit_kernel<<<(NCODES * D_DIM) / 256, 256, 0, stream>>>(W, Whi, Wlo);
  rowsq_kernel<<<(NCODES + 255) / 256, 256, 0, stream>>>(W, c2, NCODES);
  rowsq_kernel<<<(M_TOTAL + 255) / 256, 256, 0, stream>>>(V, v2, M_TOTAL);
  vq_mfma_kernel<<<dim3(M_TOTAL / 128, NCODES / 256), 256, 0, stream>>>(V, Whi, v2, c2, pk);
  gather_kernel<<<M_TOTAL, 256, 0, stream>>>(V, W, pk, out, out + OUT_OFF_IDX, lossPartial);
  finalize_kernel<<<1, 256, 0, stream>>>(lossPartial, out + OUT_OFF_LOSS);
}